// Round 6
// baseline (418.594 us; speedup 1.0000x reference)
//
#include <hip/hip_runtime.h>
#include <stdint.h>

#define N_USER 100000
#define M_ITEM 50000
#define N_NODE 150000
#define B_SEED 2048
#define S_NB 20
#define UBLK 6250            // N_USER/16
#define IBLK 3125            // M_ITEM/16

typedef __bf16   bf16x8 __attribute__((ext_vector_type(8)));
typedef float    f32x4  __attribute__((ext_vector_type(4)));
typedef uint32_t u32x4  __attribute__((ext_vector_type(4)));

__device__ __forceinline__ uint16_t f2bf(float f) {
    uint32_t u = __float_as_uint(f);
    return (uint16_t)((u + 0x7FFFu + ((u >> 16) & 1u)) >> 16);   // RNE
}
__device__ __forceinline__ uint32_t pack2bf(float a, float b) {
    return (uint32_t)f2bf(a) | ((uint32_t)f2bf(b) << 16);
}
__device__ __forceinline__ float bf2f(uint16_t u) {
    return __uint_as_float(((uint32_t)u) << 16);
}

union BF8 { bf16x8 v; uint32_t u[4]; };

__device__ __forceinline__ bf16x8 pack8v(f32x4 lo, f32x4 hi) {
    BF8 r;
    r.u[0] = pack2bf(lo[0], lo[1]); r.u[1] = pack2bf(lo[2], lo[3]);
    r.u[2] = pack2bf(hi[0], hi[1]); r.u[3] = pack2bf(hi[2], hi[3]);
    return r.v;
}
// exact masked fragment (K-tails where W is nonzero, placement matters)
__device__ __forceinline__ bf16x8 ldf32x8_mask(const float* rowp, int base, int limit) {
    BF8 r;
#pragma unroll
    for (int h = 0; h < 4; ++h) {
        const int k0 = base + 2 * h;
        const float a = (k0     < limit) ? rowp[k0]     : 0.f;
        const float b = (k0 + 1 < limit) ? rowp[k0 + 1] : 0.f;
        r.u[h] = pack2bf(a, b);
    }
    return r.v;
}

// mean of 10 feat_emb rows, cols [off, off+32) per-lane octet at +g4*8 built in
__device__ __forceinline__ bf16x8 feat_frag(const float* __restrict__ fe,
                                            const int* fi, int off) {
    f32x4 s0 = {0,0,0,0}, s1 = {0,0,0,0};
    f32x4 a[5], b[5];
#pragma unroll
    for (int j = 0; j < 5; ++j) {
        const float* p = fe + (size_t)fi[j] * 64 + off;
        a[j] = *(const f32x4*)p; b[j] = *(const f32x4*)(p + 4);
    }
#pragma unroll
    for (int j = 0; j < 5; ++j) { s0 += a[j]; s1 += b[j]; }
#pragma unroll
    for (int j = 0; j < 5; ++j) {
        const float* p = fe + (size_t)fi[5 + j] * 64 + off;
        a[j] = *(const f32x4*)p; b[j] = *(const f32x4*)(p + 4);
    }
#pragma unroll
    for (int j = 0; j < 5; ++j) { s0 += a[j]; s1 += b[j]; }
    return pack8v(s0 * 0.1f, s1 * 0.1f);
}

// mean of 8 word_emb rows (32 cols each), per-lane octet at +off
__device__ __forceinline__ bf16x8 text_frag(const float* __restrict__ we,
                                            int4 t0, int4 t1, int off) {
    f32x4 s0 = {0,0,0,0}, s1 = {0,0,0,0};
    f32x4 a[4], b[4];
    const float* p;
    p = we + (size_t)t0.x * 32 + off; a[0] = *(const f32x4*)p; b[0] = *(const f32x4*)(p + 4);
    p = we + (size_t)t0.y * 32 + off; a[1] = *(const f32x4*)p; b[1] = *(const f32x4*)(p + 4);
    p = we + (size_t)t0.z * 32 + off; a[2] = *(const f32x4*)p; b[2] = *(const f32x4*)(p + 4);
    p = we + (size_t)t0.w * 32 + off; a[3] = *(const f32x4*)p; b[3] = *(const f32x4*)(p + 4);
#pragma unroll
    for (int j = 0; j < 4; ++j) { s0 += a[j]; s1 += b[j]; }
    p = we + (size_t)t1.x * 32 + off; a[0] = *(const f32x4*)p; b[0] = *(const f32x4*)(p + 4);
    p = we + (size_t)t1.y * 32 + off; a[1] = *(const f32x4*)p; b[1] = *(const f32x4*)(p + 4);
    p = we + (size_t)t1.z * 32 + off; a[2] = *(const f32x4*)p; b[2] = *(const f32x4*)(p + 4);
    p = we + (size_t)t1.w * 32 + off; a[3] = *(const f32x4*)p; b[3] = *(const f32x4*)(p + 4);
#pragma unroll
    for (int j = 0; j < 4; ++j) { s0 += a[j]; s1 += b[j]; }
    return pack8v(s0 * 0.125f, s1 * 0.125f);
}

// ---------------------------------------------------------------------------
// One fused prep launch (WTU | WTI | WvT0 | WwT0), permuted K:
// [0,64) feat | [64,160) text | [160,224) id | [224,256) numeric
// | [256,576) word300 | [576,1344) sent768 (items)
// ---------------------------------------------------------------------------
__global__ void prep_kernel(const float* __restrict__ Wproj_u, const float* __restrict__ Wnum_u,
                            const float* __restrict__ Wproj_i, const float* __restrict__ Wnum_i,
                            const float* __restrict__ Wv0, const float* __restrict__ Ww0,
                            uint16_t* __restrict__ WTU, uint16_t* __restrict__ WTI,
                            uint16_t* __restrict__ WvT, uint16_t* __restrict__ WwT)
{
    const int idx = blockIdx.x * 256 + threadIdx.x;
    if (idx < 36864) {
        const int d = idx / 576, kp = idx - d * 576;
        float v = 0.f;
        if (kp < 160)      v = Wproj_u[(64 + kp) * 64 + d];
        else if (kp < 224) v = Wproj_u[(kp - 160) * 64 + d];
        else if (kp < 256) { const int j = kp - 224; if (j < 10)  v = Wnum_u[j * 64 + d]; }
        else               { const int j = kp - 256; if (j < 300) v = Wproj_u[(224 + j) * 64 + d]; }
        WTU[d * 576 + kp] = f2bf(v);
    } else if (idx < 122880) {
        const int i2 = idx - 36864;
        const int d = i2 / 1344, kp = i2 - d * 1344;
        float v = 0.f;
        if (kp < 160)      v = Wproj_i[(64 + kp) * 64 + d];
        else if (kp < 224) v = Wproj_i[(kp - 160) * 64 + d];
        else if (kp < 256) { const int j = kp - 224; if (j < 10)  v = Wnum_i[j * 64 + d]; }
        else if (kp < 576) { const int j = kp - 256; if (j < 300) v = Wproj_i[(224 + j) * 64 + d]; }
        else               { const int j = kp - 576; v = Wproj_i[(524 + j) * 64 + d]; }
        WTI[d * 1344 + kp] = f2bf(v);
    } else {
        const int i2 = idx - 122880;
        if (i2 < 4096) { const int d = i2 >> 6, k = i2 & 63;  WvT[d * 64 + k]  = f2bf(Wv0[k * 64 + d]); }
        else           { const int j = i2 - 4096;
                         const int d = j >> 7, k = j & 127;   WwT[d * 128 + k] = f2bf(Ww0[k * 64 + d]); }
    }
}

// ---------------------------------------------------------------------------
// Fused projection, K-split across 4 waves, deep load batching.
// Wave k-step map (kb = byte-32 offset in permuted WT):
//  w0: feat ks0 (kb0)         + w300 j{0,4,8}
//  w1: feat ks1 (kb32)        + w300 j{1,5}
//  w2: text src0(kb64), src2(kb128) + id h0(kb160) + w300 j{2,6}
//  w3: text src1(kb96) + id h1(kb192) + num(kb224) + w300 j{3,7} + tail j9(kb544)
//  items: + sent768 j' = w+4i, i<6 (kb 576+32j')
// ---------------------------------------------------------------------------
__global__ __attribute__((amdgpu_flat_work_group_size(256, 256)))
           __attribute__((amdgpu_waves_per_eu(3, 3)))
void proj_kernel(
    const float* __restrict__ u_id,  const int* __restrict__ ufi,
    const float* __restrict__ ufe,   const int* __restrict__ uti,
    const float* __restrict__ i_id,  const int* __restrict__ ifi,
    const float* __restrict__ ife,   const int* __restrict__ iti,
    const float* __restrict__ word_emb,
    const float* __restrict__ uw300, const float* __restrict__ iw300,
    const float* __restrict__ is768,
    const float* __restrict__ unum,  const float* __restrict__ inum,
    const uint16_t* __restrict__ WTU, const uint16_t* __restrict__ WTI,
    const float* __restrict__ bproj_u, const float* __restrict__ bnum_u,
    const float* __restrict__ bproj_i, const float* __restrict__ bnum_i,
    uint16_t* __restrict__ xout)
{
    __shared__ float R[4 * 16 * 68];   // padded stride 68

    const int t = threadIdx.x;
    const int w = t >> 6, l = t & 63;
    const int l15 = l & 15, g4 = l >> 4;
    const bool item = blockIdx.x >= UBLK;
    const int tile = item ? (blockIdx.x - UBLK) : blockIdx.x;
    const int nloc = tile * 16 + l15;

    const float* id_emb   = item ? i_id  : u_id;
    const int*   feat_idx = item ? ifi   : ufi;
    const float* feat_emb = item ? ife   : ufe;
    const int*   text_idx = item ? iti   : uti;
    const float* word300  = item ? iw300 : uw300;
    const float* numeric  = item ? inum  : unum;
    const uint16_t* WT    = item ? WTI   : WTU;
    const int KPADP       = item ? 1344  : 576;

    f32x4 acc[4] = {};
    const uint16_t* WTp[4];
#pragma unroll
    for (int db = 0; db < 4; ++db)
        WTp[db] = WT + (size_t)(db * 16 + l15) * KPADP + g4 * 8;

    auto MM = [&](bf16x8 af, int kb) {
#pragma unroll
        for (int db = 0; db < 4; ++db) {
            const bf16x8 bfr = *reinterpret_cast<const bf16x8*>(WTp[db] + kb);
            acc[db] = __builtin_amdgcn_mfma_f32_16x16x32_bf16(af, bfr, acc[db], 0, 0, 0);
        }
    };

    // ================= issue phase: indices =================
    int fi[10];
    int4 tA0, tA1, tB0, tB1;
    if (w < 2) {
        const int* fip = feat_idx + (size_t)nloc * 10;
#pragma unroll
        for (int j = 0; j < 10; ++j) fi[j] = fip[j];
    } else {
        const int srcA = (w == 2) ? 0 : 1;
        const int* tp = text_idx + ((size_t)nloc * 3 + srcA) * 8;
        tA0 = *(const int4*)tp; tA1 = *(const int4*)(tp + 4);
        if (w == 2) {
            const int* tq = text_idx + ((size_t)nloc * 3 + 2) * 8;
            tB0 = *(const int4*)tq; tB1 = *(const int4*)(tq + 4);
        }
    }

    // ================= issue phase: dense loads =================
    const float* wr = word300 + (size_t)nloc * 300;
    f32x4 wv[3][2];
    const int NJ = (w == 0) ? 3 : 2;
#pragma unroll
    for (int i = 0; i < 3; ++i) {
        if (i < NJ) {
            const int j = (w == 0) ? 4 * i : (w + 4 * i);
            const float* p = wr + j * 32 + g4 * 8;
            wv[i][0] = *(const f32x4*)p; wv[i][1] = *(const f32x4*)(p + 4);
        }
    }
    f32x4 idv[2];
    if (w >= 2) {
        const float* p = id_emb + (size_t)nloc * 64 + (w - 2) * 32 + g4 * 8;
        idv[0] = *(const f32x4*)p; idv[1] = *(const f32x4*)(p + 4);
    }
    bf16x8 numf, tailf;
    if (w == 3) {
        numf  = ldf32x8_mask(numeric + (size_t)nloc * 10, g4 * 8, 10);
        tailf = ldf32x8_mask(wr, 288 + g4 * 8, 300);
    }
    f32x4 sv[6][2];
    if (item) {
        const float* sr = is768 + (size_t)nloc * 768;
#pragma unroll
        for (int i = 0; i < 6; ++i) {
            const float* p = sr + (w + 4 * i) * 32 + g4 * 8;
            sv[i][0] = *(const f32x4*)p; sv[i][1] = *(const f32x4*)(p + 4);
        }
    }

    // ================= gather chains (dense loads in flight) =================
    if (w < 2) {
        MM(feat_frag(feat_emb, fi, w * 32 + g4 * 8), w * 32);
    } else if (w == 2) {
        MM(text_frag(word_emb, tA0, tA1, g4 * 8), 64);
        MM(text_frag(word_emb, tB0, tB1, g4 * 8), 128);
    } else {
        MM(text_frag(word_emb, tA0, tA1, g4 * 8), 96);
    }

    // ================= dense MMs =================
#pragma unroll
    for (int i = 0; i < 3; ++i) {
        if (i < NJ) {
            const int j = (w == 0) ? 4 * i : (w + 4 * i);
            MM(pack8v(wv[i][0], wv[i][1]), 256 + 32 * j);
        }
    }
    if (w >= 2) MM(pack8v(idv[0], idv[1]), 160 + 32 * (w - 2));
    if (w == 3) { MM(numf, 224); MM(tailf, 544); }
    if (item) {
#pragma unroll
        for (int i = 0; i < 6; ++i)
            MM(pack8v(sv[i][0], sv[i][1]), 576 + 32 * (w + 4 * i));
    }

    // ================= LDS reduce across waves =================
    {
        float* Rw = R + w * (16 * 68);
#pragma unroll
        for (int db = 0; db < 4; ++db)
#pragma unroll
            for (int r = 0; r < 4; ++r)
                Rw[(g4 * 4 + r) * 68 + db * 16 + l15] = acc[db][r];
    }
    __syncthreads();

    const int n  = t >> 4;           // node 0..15
    const int dq = t & 15;           // dim quad
    const float* Rn = R + n * 68 + dq * 4;
    f32x4 s = *(const f32x4*)Rn + *(const f32x4*)(Rn + 1088)
            + *(const f32x4*)(Rn + 2176) + *(const f32x4*)(Rn + 3264);

    const float* bp = item ? bproj_i : bproj_u;
    const float* bn = item ? bnum_i  : bnum_u;
    const float4 b1 = *(const float4*)(bp + dq * 4);
    const float4 b2 = *(const float4*)(bn + dq * 4);
    const uint32_t o0 = pack2bf(s[0] + b1.x + b2.x, s[1] + b1.y + b2.y);
    const uint32_t o1 = pack2bf(s[2] + b1.z + b2.z, s[3] + b1.w + b2.w);
    const size_t obase = ((size_t)(item ? N_USER : 0) + (size_t)tile * 16 + n) * 64 + dq * 4;
    *(uint2*)(xout + obase) = make_uint2(o0, o1);
}

// ---------------------------------------------------------------------------
// xv = x @ Wv0 + bv0   (bf16 in/out, per node)
// ---------------------------------------------------------------------------
__global__ __launch_bounds__(256) void xv_kernel(
    const uint16_t* __restrict__ x, const uint16_t* __restrict__ WvT,
    const float* __restrict__ bv, uint16_t* __restrict__ xv, int n)
{
    const int t = threadIdx.x;
    const int w = t >> 6, l = t & 63, l15 = l & 15, g4 = l >> 4;
    const int node = blockIdx.x * 64 + w * 16 + l15;
    const int node_c = node < n ? node : n - 1;

    f32x4 acc[4] = {};
    const uint16_t* WTb = WvT + l15 * 64 + g4 * 8;
#pragma unroll
    for (int ks = 0; ks < 2; ++ks) {
        const bf16x8 af = *reinterpret_cast<const bf16x8*>(x + (size_t)node_c * 64 + ks * 32 + g4 * 8);
#pragma unroll
        for (int db = 0; db < 4; ++db) {
            const bf16x8 bfr = *reinterpret_cast<const bf16x8*>(WTb + db * 16 * 64 + ks * 32);
            acc[db] = __builtin_amdgcn_mfma_f32_16x16x32_bf16(af, bfr, acc[db], 0, 0, 0);
        }
    }
    const int node_base = blockIdx.x * 64 + w * 16 + g4 * 4;
#pragma unroll
    for (int db = 0; db < 4; ++db) {
        const int d = db * 16 + l15;
        const float bias = bv[d];
#pragma unroll
        for (int r = 0; r < 4; ++r) {
            const int nn = node_base + r;
            if (nn < n) xv[(size_t)nn * 64 + d] = f2bf(acc[db][r] + bias);
        }
    }
}

// ---------------------------------------------------------------------------
// SAGE layer-0 (MFMA): out[r] = act( [ x[self[r]] | mean_j xv[neigh[r,j]] ] @ Ww0 + bw0 )
// ---------------------------------------------------------------------------
__global__ __launch_bounds__(256) void sage_mfma_kernel(
    const uint16_t* __restrict__ x, const uint16_t* __restrict__ xv,
    const int* __restrict__ self_idx, const int* __restrict__ neigh_idx,
    const uint16_t* __restrict__ WwT, const float* __restrict__ bw,
    uint16_t* __restrict__ out, int relu)
{
    const int t = threadIdx.x;
    const int w = t >> 6, l = t & 63, l15 = l & 15, g4 = l >> 4;
    const int r = blockIdx.x * 64 + w * 16 + l15;
    const int sidx = self_idx[r];
    const int* ni = neigh_idx + (size_t)r * S_NB;

    f32x4 acc[4] = {};
    const uint16_t* WTb = WwT + l15 * 128 + g4 * 8;

    auto MM = [&](bf16x8 af, int kb) {
#pragma unroll
        for (int db = 0; db < 4; ++db) {
            const bf16x8 bfr = *reinterpret_cast<const bf16x8*>(WTb + db * 16 * 128 + kb);
            acc[db] = __builtin_amdgcn_mfma_f32_16x16x32_bf16(af, bfr, acc[db], 0, 0, 0);
        }
    };

#pragma unroll
    for (int ks = 0; ks < 2; ++ks) {
        const bf16x8 af = *reinterpret_cast<const bf16x8*>(x + (size_t)sidx * 64 + ks * 32 + g4 * 8);
        MM(af, ks * 32);
    }
#pragma unroll
    for (int ks = 0; ks < 2; ++ks) {
        float ev[4] = {0.f, 0.f, 0.f, 0.f}, od[4] = {0.f, 0.f, 0.f, 0.f};
#pragma unroll
        for (int j = 0; j < S_NB; ++j) {
            const u32x4 v = *reinterpret_cast<const u32x4*>(xv + (size_t)ni[j] * 64 + ks * 32 + g4 * 8);
#pragma unroll
            for (int q = 0; q < 4; ++q) {
                ev[q] += __uint_as_float(v[q] << 16);
                od[q] += __uint_as_float(v[q] & 0xffff0000u);
            }
        }
        BF8 m;
#pragma unroll
        for (int q = 0; q < 4; ++q) m.u[q] = pack2bf(ev[q] * (1.f / S_NB), od[q] * (1.f / S_NB));
        MM(m.v, 64 + ks * 32);
    }

    const int rb = blockIdx.x * 64 + w * 16 + g4 * 4;
#pragma unroll
    for (int db = 0; db < 4; ++db) {
        const int d = db * 16 + l15;
        const float bias = bw[d];
#pragma unroll
        for (int rr = 0; rr < 4; ++rr) {
            float h = acc[db][rr] + bias;
            if (relu) h = fmaxf(h, 0.f);
            out[(size_t)(rb + rr) * 64 + d] = f2bf(h);
        }
    }
}

// ---------------------------------------------------------------------------
// Final layer (fp32 shfl GEMV, 2048 rows)
// ---------------------------------------------------------------------------
__global__ __launch_bounds__(256) void final_kernel(
    const uint16_t* __restrict__ h0, const uint16_t* __restrict__ h1,
    const float* __restrict__ Wv, const float* __restrict__ bv,
    const float* __restrict__ Ww, const float* __restrict__ bw,
    float* __restrict__ out)
{
    __shared__ float WvL[64 * 64];
    __shared__ float WwL[128 * 64];
    const int t = threadIdx.x;
    for (int i = t; i < 64 * 64; i += 256)  WvL[i] = Wv[i];
    for (int i = t; i < 128 * 64; i += 256) WwL[i] = Ww[i];
    __syncthreads();

    const int wave = t >> 6, lane = t & 63;
    const int base = blockIdx.x * 32 + wave * 8;
    const float bvl = bv[lane], bwl = bw[lane];

    for (int i = 0; i < 8; ++i) {
        const int b = base + i;
        float m = 0.f;
#pragma unroll
        for (int s = 0; s < S_NB; ++s)
            m += bf2f(h1[(size_t)(b * S_NB + s) * 64 + lane]);
        m *= (1.f / S_NB);

        float agg = bvl;
#pragma unroll 8
        for (int k = 0; k < 64; ++k)
            agg += __shfl(m, k) * WvL[k * 64 + lane];

        const float selfv = bf2f(h0[(size_t)b * 64 + lane]);
        float h = bwl;
#pragma unroll 8
        for (int k = 0; k < 64; ++k)
            h += __shfl(selfv, k) * WwL[k * 64 + lane];
#pragma unroll 8
        for (int k = 0; k < 64; ++k)
            h += __shfl(agg, k) * WwL[(64 + k) * 64 + lane];

        out[(size_t)b * 64 + lane] = h;
    }
}

// ---------------------------------------------------------------------------
extern "C" void kernel_launch(void* const* d_in, const int* in_sizes, int n_in,
                              void* d_out, int out_size, void* d_ws, size_t ws_size,
                              hipStream_t stream)
{
    const int*   seeds   = (const int*)d_in[0];
    const int*   neigh1  = (const int*)d_in[1];
    const int*   neigh2  = (const int*)d_in[2];
    const int*   ufi     = (const int*)d_in[3];
    const int*   ifi     = (const int*)d_in[4];
    const int*   uti     = (const int*)d_in[5];
    const int*   iti     = (const int*)d_in[6];
    const float* u_id    = (const float*)d_in[7];
    const float* i_id    = (const float*)d_in[8];
    const float* ufe     = (const float*)d_in[9];
    const float* ife     = (const float*)d_in[10];
    const float* wemb    = (const float*)d_in[11];
    const float* uw300   = (const float*)d_in[12];
    const float* iw300   = (const float*)d_in[13];
    const float* is768   = (const float*)d_in[14];
    const float* unum    = (const float*)d_in[15];
    const float* inum    = (const float*)d_in[16];
    const float* Wnum_u  = (const float*)d_in[17];
    const float* bnum_u  = (const float*)d_in[18];
    const float* Wnum_i  = (const float*)d_in[19];
    const float* bnum_i  = (const float*)d_in[20];
    const float* Wproj_u = (const float*)d_in[21];
    const float* bproj_u = (const float*)d_in[22];
    const float* Wproj_i = (const float*)d_in[23];
    const float* bproj_i = (const float*)d_in[24];
    const float* W_w     = (const float*)d_in[25];
    const float* b_w     = (const float*)d_in[26];
    const float* W_v     = (const float*)d_in[27];
    const float* b_v     = (const float*)d_in[28];

    // ws layout (uint16 elements)
    uint16_t* WTU  = (uint16_t*)d_ws;                       // 64*576
    uint16_t* WTI  = WTU  + 36864;                          // 64*1344
    uint16_t* WvT0 = WTI  + 86016;                          // 64*64
    uint16_t* WwT0 = WvT0 + 4096;                           // 64*128
    uint16_t* xbf  = WwT0 + 8192;                           // N_NODE*64
    uint16_t* xvbf = xbf  + (size_t)N_NODE * 64;            // N_NODE*64
    uint16_t* h1bf = xvbf + (size_t)N_NODE * 64;            // 40960*64
    uint16_t* h0bf = h1bf + (size_t)B_SEED * S_NB * 64;     // 2048*64
    float* outp = (float*)d_out;

    prep_kernel<<<528, 256, 0, stream>>>(
        Wproj_u, Wnum_u, Wproj_i, Wnum_i, W_v, W_w, WTU, WTI, WvT0, WwT0);

    proj_kernel<<<UBLK + IBLK, 256, 0, stream>>>(
        u_id, ufi, ufe, uti, i_id, ifi, ife, iti, wemb,
        uw300, iw300, is768, unum, inum,
        WTU, WTI, bproj_u, bnum_u, bproj_i, bnum_i, xbf);

    xv_kernel<<<(N_NODE + 63) / 64, 256, 0, stream>>>(xbf, WvT0, b_v, xvbf, N_NODE);

    sage_mfma_kernel<<<(B_SEED * S_NB) / 64, 256, 0, stream>>>(
        xbf, xvbf, neigh1, neigh2, WwT0, b_w, h1bf, 1);
    sage_mfma_kernel<<<B_SEED / 64, 256, 0, stream>>>(
        xbf, xvbf, seeds, neigh1, WwT0, b_w, h0bf, 1);

    final_kernel<<<B_SEED / 32, 256, 0, stream>>>(
        h0bf, h1bf, W_v + 4096, b_v + 64, W_w + 8192, b_w + 64, outp);
}

// Round 7
// 389.053 us; speedup vs baseline: 1.0759x; 1.0759x over previous
//
#include <hip/hip_runtime.h>
#include <hip/hip_bf16.h>
#include <stdint.h>

#define N_USER 100000
#define M_ITEM 50000
#define N_NODE 150000
#define B_SEED 2048
#define S_NB 20
#define UBLK2 1563           // ceil(100000/64)
#define IBLK2 782            // ceil(50000/64)

typedef __bf16   bf16x8 __attribute__((ext_vector_type(8)));
typedef float    f32x4  __attribute__((ext_vector_type(4)));
typedef uint32_t u32x4  __attribute__((ext_vector_type(4)));

__device__ __forceinline__ uint16_t f2bf(float f) {
    uint32_t u = __float_as_uint(f);
    return (uint16_t)((u + 0x7FFFu + ((u >> 16) & 1u)) >> 16);   // RNE
}
__device__ __forceinline__ uint32_t pk2(float a, float b) {      // packed HW cvt (RNE)
    __hip_bfloat162 h = __float22bfloat162_rn(make_float2(a, b));
    return *reinterpret_cast<uint32_t*>(&h);
}
__device__ __forceinline__ float bf2f(uint16_t u) {
    return __uint_as_float(((uint32_t)u) << 16);
}

union BF8 { bf16x8 v; uint32_t u[4]; uint2 d2[2]; };

__device__ __forceinline__ bf16x8 pack8v(f32x4 lo, f32x4 hi) {
    BF8 r;
    r.u[0] = pk2(lo[0], lo[1]); r.u[1] = pk2(lo[2], lo[3]);
    r.u[2] = pk2(hi[0], hi[1]); r.u[3] = pk2(hi[2], hi[3]);
    return r.v;
}
__device__ __forceinline__ bf16x8 ldf32x8_mask(const float* rowp, int base, int limit) {
    BF8 r;
#pragma unroll
    for (int h = 0; h < 4; ++h) {
        const int k0 = base + 2 * h;
        const float a = (k0     < limit) ? rowp[k0]     : 0.f;
        const float b = (k0 + 1 < limit) ? rowp[k0 + 1] : 0.f;
        r.u[h] = pk2(a, b);
    }
    return r.v;
}

// ---------------------------------------------------------------------------
// prep: WT permuted-K transposed weights (bf16) + small layer weights.
// k' [0,160): feat|text (orig Wproj rows 64..223)
// k' [160,192): numeric (10 valid)
// k' [192,256): id (orig rows 0..63)
// k' [256,576): word300 (300 valid)
// k' [576,1344): sent768 (items)
// ---------------------------------------------------------------------------
__global__ void prep_kernel(const float* __restrict__ Wproj_u, const float* __restrict__ Wnum_u,
                            const float* __restrict__ Wproj_i, const float* __restrict__ Wnum_i,
                            const float* __restrict__ Wv0, const float* __restrict__ Ww0,
                            uint16_t* __restrict__ WTU, uint16_t* __restrict__ WTI,
                            uint16_t* __restrict__ WvT, uint16_t* __restrict__ WwT)
{
    const int idx = blockIdx.x * 256 + threadIdx.x;   // exactly 135168
    if (idx < 36864) {
        const int d = idx / 576, kp = idx - d * 576;
        float v = 0.f;
        if (kp < 160)      v = Wproj_u[(64 + kp) * 64 + d];
        else if (kp < 192) { const int j = kp - 160; if (j < 10)  v = Wnum_u[j * 64 + d]; }
        else if (kp < 256) v = Wproj_u[(kp - 192) * 64 + d];
        else               { const int j = kp - 256; if (j < 300) v = Wproj_u[(224 + j) * 64 + d]; }
        WTU[d * 576 + kp] = f2bf(v);
    } else if (idx < 122880) {
        const int i2 = idx - 36864;
        const int d = i2 / 1344, kp = i2 - d * 1344;
        float v = 0.f;
        if (kp < 160)      v = Wproj_i[(64 + kp) * 64 + d];
        else if (kp < 192) { const int j = kp - 160; if (j < 10)  v = Wnum_i[j * 64 + d]; }
        else if (kp < 256) v = Wproj_i[(kp - 192) * 64 + d];
        else if (kp < 576) { const int j = kp - 256; if (j < 300) v = Wproj_i[(224 + j) * 64 + d]; }
        else               { const int j = kp - 576; v = Wproj_i[(524 + j) * 64 + d]; }
        WTI[d * 1344 + kp] = f2bf(v);
    } else {
        const int i2 = idx - 122880;
        if (i2 < 4096) { const int d = i2 >> 6, k = i2 & 63;  WvT[d * 64 + k]  = f2bf(Wv0[k * 64 + d]); }
        else           { const int j = i2 - 4096;
                         const int d = j >> 7, k = j & 127;   WwT[d * 128 + k] = f2bf(Ww0[k * 64 + d]); }
    }
}

// ---------------------------------------------------------------------------
// gpack: gathered segments -> A_pre[node][160] bf16.
// 8 threads (one octet) per node; d0 = lane-in-octet.
// feat: dims 8*d0..8*d0+7 of mean of 10 feat_emb rows.
// text: per src, dims 4*d0..4*d0+3 of mean of 8 word_emb rows.
// Pure gather/pack: no LDS, no MFMA, max occupancy.
// ---------------------------------------------------------------------------
__global__ __launch_bounds__(256) void gpack_kernel(
    const int* __restrict__ ufi, const int* __restrict__ ifi,
    const int* __restrict__ uti, const int* __restrict__ iti,
    const float* __restrict__ ufe, const float* __restrict__ ife,
    const float* __restrict__ wemb,
    uint16_t* __restrict__ Apre)
{
    const int gid  = blockIdx.x * 256 + threadIdx.x;
    const int node = gid >> 3;
    const int d0   = gid & 7;
    if (node >= N_NODE) return;
    const bool item = node >= N_USER;
    const int nloc  = item ? node - N_USER : node;
    const int*   fidx = (item ? ifi : ufi) + (size_t)nloc * 10;
    const int*   tidx = (item ? iti : uti) + (size_t)nloc * 24;
    const float* fe   = item ? ife : ufe;
    uint16_t* out = Apre + (size_t)node * 160;

    // ---- feat mean (10 rows), 8 dims per lane ----
    {
        f32x4 s0 = {0, 0, 0, 0}, s1 = {0, 0, 0, 0};
#pragma unroll
        for (int j = 0; j < 10; ++j) {
            const float* p = fe + (size_t)fidx[j] * 64 + 8 * d0;
            s0 += *(const f32x4*)p;
            s1 += *(const f32x4*)(p + 4);
        }
        s0 *= 0.1f; s1 *= 0.1f;
        uint4 o = make_uint4(pk2(s0[0], s0[1]), pk2(s0[2], s0[3]),
                             pk2(s1[0], s1[1]), pk2(s1[2], s1[3]));
        *(uint4*)(out + 8 * d0) = o;
    }
    // ---- text means (3 sources x 8 rows), 4 dims per lane ----
#pragma unroll
    for (int s = 0; s < 3; ++s) {
        f32x4 a = {0, 0, 0, 0};
#pragma unroll
        for (int j = 0; j < 8; ++j) {
            const float* p = wemb + (size_t)tidx[s * 8 + j] * 32 + 4 * d0;
            a += *(const f32x4*)p;
        }
        a *= 0.125f;
        *(uint2*)(out + 64 + 32 * s + 4 * d0) = make_uint2(pk2(a[0], a[1]), pk2(a[2], a[3]));
    }
}

// ---------------------------------------------------------------------------
// pgemm: x[node] = A[node] @ WT^T + bias. A-rows are pure streams now:
// ks0..4 A_pre (bf16 direct), ks5 numeric (masked), ks6..7 id,
// ks8..17 word300 (tail masked), ks18..41 sent768 (items).
// No LDS, no barriers; explicit load batches; 16 waves/CU budget.
// ---------------------------------------------------------------------------
__global__ __launch_bounds__(256, 4) void pgemm_kernel(
    const uint16_t* __restrict__ Apre,
    const float* __restrict__ u_id,  const float* __restrict__ i_id,
    const float* __restrict__ uw300, const float* __restrict__ iw300,
    const float* __restrict__ is768,
    const float* __restrict__ unum,  const float* __restrict__ inum,
    const uint16_t* __restrict__ WTU, const uint16_t* __restrict__ WTI,
    const float* __restrict__ bproj_u, const float* __restrict__ bnum_u,
    const float* __restrict__ bproj_i, const float* __restrict__ bnum_i,
    uint16_t* __restrict__ xout)
{
    const int t = threadIdx.x;
    const int w = t >> 6, l = t & 63;
    const int l15 = l & 15, g4 = l >> 4;
    const bool item = blockIdx.x >= UBLK2;
    const int tile  = item ? (blockIdx.x - UBLK2) : blockIdx.x;
    const int ntype = item ? M_ITEM : N_USER;
    const int nloc0 = tile * 64 + w * 16 + l15;
    const int nloc  = nloc0 < ntype ? nloc0 : ntype - 1;
    const int node  = (item ? N_USER : 0) + nloc;

    const uint16_t* WT = item ? WTI : WTU;
    const int KP       = item ? 1344 : 576;

    f32x4 acc[4] = {};
    const uint16_t* WTb = WT + (size_t)l15 * KP + g4 * 8;

    auto MM = [&](bf16x8 af, int kb) {
#pragma unroll
        for (int db = 0; db < 4; ++db) {
            const bf16x8 bfr = *reinterpret_cast<const bf16x8*>(WTb + (size_t)db * 16 * KP + kb);
            acc[db] = __builtin_amdgcn_mfma_f32_16x16x32_bf16(af, bfr, acc[db], 0, 0, 0);
        }
    };

    // ---- ks0..4: A_pre, bf16 direct to fragment ----
    {
        const uint16_t* ap = Apre + (size_t)node * 160 + g4 * 8;
        bf16x8 af[5];
#pragma unroll
        for (int ks = 0; ks < 5; ++ks) af[ks] = *(const bf16x8*)(ap + ks * 32);
#pragma unroll
        for (int ks = 0; ks < 5; ++ks) MM(af[ks], ks * 32);
    }
    // ---- ks5: numeric (10 valid) ----
    MM(ldf32x8_mask((item ? inum : unum) + (size_t)nloc * 10, g4 * 8, 10), 160);
    // ---- ks6..7: id ----
    {
        const float* idr = (item ? i_id : u_id) + (size_t)nloc * 64 + g4 * 8;
        f32x4 a0 = *(const f32x4*)idr,        a1 = *(const f32x4*)(idr + 4);
        f32x4 b0 = *(const f32x4*)(idr + 32), b1 = *(const f32x4*)(idr + 36);
        MM(pack8v(a0, a1), 192);
        MM(pack8v(b0, b1), 224);
    }
    // ---- ks8..17: word300 (batch 5 + 4, tail masked) ----
    {
        const float* wr = (item ? iw300 : uw300) + (size_t)nloc * 300 + g4 * 8;
        f32x4 va[5][2];
#pragma unroll
        for (int u = 0; u < 5; ++u) {
            const float* p = wr + u * 32;
            va[u][0] = *(const f32x4*)p; va[u][1] = *(const f32x4*)(p + 4);
        }
#pragma unroll
        for (int u = 0; u < 5; ++u) MM(pack8v(va[u][0], va[u][1]), 256 + u * 32);
#pragma unroll
        for (int u = 0; u < 4; ++u) {
            const float* p = wr + (5 + u) * 32;
            va[u][0] = *(const f32x4*)p; va[u][1] = *(const f32x4*)(p + 4);
        }
#pragma unroll
        for (int u = 0; u < 4; ++u) MM(pack8v(va[u][0], va[u][1]), 256 + (5 + u) * 32);
        MM(ldf32x8_mask(wr - g4 * 8, 288 + g4 * 8, 300), 544);
    }
    // ---- ks18..41: sent768 (items), 4 batches of 6 ----
    if (item) {
        const float* sr = is768 + (size_t)nloc * 768 + g4 * 8;
#pragma unroll
        for (int b = 0; b < 4; ++b) {
            f32x4 va[6][2];
#pragma unroll
            for (int u = 0; u < 6; ++u) {
                const float* p = sr + (b * 6 + u) * 32;
                va[u][0] = *(const f32x4*)p; va[u][1] = *(const f32x4*)(p + 4);
            }
#pragma unroll
            for (int u = 0; u < 6; ++u)
                MM(pack8v(va[u][0], va[u][1]), 576 + (b * 6 + u) * 32);
        }
    }

    // ---- epilogue: row = g4*4+r (node-in-64), col d = db*16+l15 ----
    const int nb_out = tile * 64 + w * 16 + g4 * 4;
    const float* bp = item ? bproj_i : bproj_u;
    const float* bn = item ? bnum_i  : bnum_u;
    uint16_t* xo = xout + (size_t)(item ? N_USER : 0) * 64;
#pragma unroll
    for (int db = 0; db < 4; ++db) {
        const int d = db * 16 + l15;
        const float bias = bp[d] + bn[d];
#pragma unroll
        for (int r = 0; r < 4; ++r) {
            const int nn = nb_out + r;
            if (nn < ntype) xo[(size_t)nn * 64 + d] = f2bf(acc[db][r] + bias);
        }
    }
}

// ---------------------------------------------------------------------------
// xv = x @ Wv0 + bv0   (bf16 in/out, per node)
// ---------------------------------------------------------------------------
__global__ __launch_bounds__(256) void xv_kernel(
    const uint16_t* __restrict__ x, const uint16_t* __restrict__ WvT,
    const float* __restrict__ bv, uint16_t* __restrict__ xv, int n)
{
    const int t = threadIdx.x;
    const int w = t >> 6, l = t & 63, l15 = l & 15, g4 = l >> 4;
    const int node = blockIdx.x * 64 + w * 16 + l15;
    const int node_c = node < n ? node : n - 1;

    f32x4 acc[4] = {};
    const uint16_t* WTb = WvT + l15 * 64 + g4 * 8;
#pragma unroll
    for (int ks = 0; ks < 2; ++ks) {
        const bf16x8 af = *reinterpret_cast<const bf16x8*>(x + (size_t)node_c * 64 + ks * 32 + g4 * 8);
#pragma unroll
        for (int db = 0; db < 4; ++db) {
            const bf16x8 bfr = *reinterpret_cast<const bf16x8*>(WTb + db * 16 * 64 + ks * 32);
            acc[db] = __builtin_amdgcn_mfma_f32_16x16x32_bf16(af, bfr, acc[db], 0, 0, 0);
        }
    }
    const int node_base = blockIdx.x * 64 + w * 16 + g4 * 4;
#pragma unroll
    for (int db = 0; db < 4; ++db) {
        const int d = db * 16 + l15;
        const float bias = bv[d];
#pragma unroll
        for (int r = 0; r < 4; ++r) {
            const int nn = node_base + r;
            if (nn < n) xv[(size_t)nn * 64 + d] = f2bf(acc[db][r] + bias);
        }
    }
}

// ---------------------------------------------------------------------------
// SAGE layer-0 (MFMA): out[r] = act( [ x[self[r]] | mean_j xv[neigh[r,j]] ] @ Ww0 + bw0 )
// ---------------------------------------------------------------------------
__global__ __launch_bounds__(256) void sage_mfma_kernel(
    const uint16_t* __restrict__ x, const uint16_t* __restrict__ xv,
    const int* __restrict__ self_idx, const int* __restrict__ neigh_idx,
    const uint16_t* __restrict__ WwT, const float* __restrict__ bw,
    uint16_t* __restrict__ out, int relu)
{
    const int t = threadIdx.x;
    const int w = t >> 6, l = t & 63, l15 = l & 15, g4 = l >> 4;
    const int r = blockIdx.x * 64 + w * 16 + l15;
    const int sidx = self_idx[r];
    const int* ni = neigh_idx + (size_t)r * S_NB;

    f32x4 acc[4] = {};
    const uint16_t* WTb = WwT + l15 * 128 + g4 * 8;

    auto MM = [&](bf16x8 af, int kb) {
#pragma unroll
        for (int db = 0; db < 4; ++db) {
            const bf16x8 bfr = *reinterpret_cast<const bf16x8*>(WTb + db * 16 * 128 + kb);
            acc[db] = __builtin_amdgcn_mfma_f32_16x16x32_bf16(af, bfr, acc[db], 0, 0, 0);
        }
    };

#pragma unroll
    for (int ks = 0; ks < 2; ++ks) {
        const bf16x8 af = *reinterpret_cast<const bf16x8*>(x + (size_t)sidx * 64 + ks * 32 + g4 * 8);
        MM(af, ks * 32);
    }
#pragma unroll
    for (int ks = 0; ks < 2; ++ks) {
        float ev[4] = {0.f, 0.f, 0.f, 0.f}, od[4] = {0.f, 0.f, 0.f, 0.f};
#pragma unroll
        for (int j = 0; j < S_NB; ++j) {
            const u32x4 v = *reinterpret_cast<const u32x4*>(xv + (size_t)ni[j] * 64 + ks * 32 + g4 * 8);
#pragma unroll
            for (int q = 0; q < 4; ++q) {
                ev[q] += __uint_as_float(v[q] << 16);
                od[q] += __uint_as_float(v[q] & 0xffff0000u);
            }
        }
        BF8 m;
#pragma unroll
        for (int q = 0; q < 4; ++q) m.u[q] = pk2(ev[q] * (1.f / S_NB), od[q] * (1.f / S_NB));
        MM(m.v, 64 + ks * 32);
    }

    const int rb = blockIdx.x * 64 + w * 16 + g4 * 4;
#pragma unroll
    for (int db = 0; db < 4; ++db) {
        const int d = db * 16 + l15;
        const float bias = bw[d];
#pragma unroll
        for (int rr = 0; rr < 4; ++rr) {
            float h = acc[db][rr] + bias;
            if (relu) h = fmaxf(h, 0.f);
            out[(size_t)(rb + rr) * 64 + d] = f2bf(h);
        }
    }
}

// ---------------------------------------------------------------------------
// Final layer (fp32 shfl GEMV, 2048 rows)
// ---------------------------------------------------------------------------
__global__ __launch_bounds__(256) void final_kernel(
    const uint16_t* __restrict__ h0, const uint16_t* __restrict__ h1,
    const float* __restrict__ Wv, const float* __restrict__ bv,
    const float* __restrict__ Ww, const float* __restrict__ bw,
    float* __restrict__ out)
{
    __shared__ float WvL[64 * 64];
    __shared__ float WwL[128 * 64];
    const int t = threadIdx.x;
    for (int i = t; i < 64 * 64; i += 256)  WvL[i] = Wv[i];
    for (int i = t; i < 128 * 64; i += 256) WwL[i] = Ww[i];
    __syncthreads();

    const int wave = t >> 6, lane = t & 63;
    const int base = blockIdx.x * 32 + wave * 8;
    const float bvl = bv[lane], bwl = bw[lane];

    for (int i = 0; i < 8; ++i) {
        const int b = base + i;
        float m = 0.f;
#pragma unroll
        for (int s = 0; s < S_NB; ++s)
            m += bf2f(h1[(size_t)(b * S_NB + s) * 64 + lane]);
        m *= (1.f / S_NB);

        float agg = bvl;
#pragma unroll 8
        for (int k = 0; k < 64; ++k)
            agg += __shfl(m, k) * WvL[k * 64 + lane];

        const float selfv = bf2f(h0[(size_t)b * 64 + lane]);
        float h = bwl;
#pragma unroll 8
        for (int k = 0; k < 64; ++k)
            h += __shfl(selfv, k) * WwL[k * 64 + lane];
#pragma unroll 8
        for (int k = 0; k < 64; ++k)
            h += __shfl(agg, k) * WwL[(64 + k) * 64 + lane];

        out[(size_t)b * 64 + lane] = h;
    }
}

// ---------------------------------------------------------------------------
extern "C" void kernel_launch(void* const* d_in, const int* in_sizes, int n_in,
                              void* d_out, int out_size, void* d_ws, size_t ws_size,
                              hipStream_t stream)
{
    const int*   seeds   = (const int*)d_in[0];
    const int*   neigh1  = (const int*)d_in[1];
    const int*   neigh2  = (const int*)d_in[2];
    const int*   ufi     = (const int*)d_in[3];
    const int*   ifi     = (const int*)d_in[4];
    const int*   uti     = (const int*)d_in[5];
    const int*   iti     = (const int*)d_in[6];
    const float* u_id    = (const float*)d_in[7];
    const float* i_id    = (const float*)d_in[8];
    const float* ufe     = (const float*)d_in[9];
    const float* ife     = (const float*)d_in[10];
    const float* wemb    = (const float*)d_in[11];
    const float* uw300   = (const float*)d_in[12];
    const float* iw300   = (const float*)d_in[13];
    const float* is768   = (const float*)d_in[14];
    const float* unum    = (const float*)d_in[15];
    const float* inum    = (const float*)d_in[16];
    const float* Wnum_u  = (const float*)d_in[17];
    const float* bnum_u  = (const float*)d_in[18];
    const float* Wnum_i  = (const float*)d_in[19];
    const float* bnum_i  = (const float*)d_in[20];
    const float* Wproj_u = (const float*)d_in[21];
    const float* bproj_u = (const float*)d_in[22];
    const float* Wproj_i = (const float*)d_in[23];
    const float* bproj_i = (const float*)d_in[24];
    const float* W_w     = (const float*)d_in[25];
    const float* b_w     = (const float*)d_in[26];
    const float* W_v     = (const float*)d_in[27];
    const float* b_v     = (const float*)d_in[28];

    // ws layout (uint16 elements):
    // WTU | WTI | WvT0 | WwT0 | xbf | UNION{ xvbf|h1bf|h0bf , A_pre }
    uint16_t* WTU  = (uint16_t*)d_ws;                       // 64*576
    uint16_t* WTI  = WTU  + 36864;                          // 64*1344
    uint16_t* WvT0 = WTI  + 86016;                          // 64*64
    uint16_t* WwT0 = WvT0 + 4096;                           // 64*128
    uint16_t* xbf  = WwT0 + 8192;                           // 150000*64
    uint16_t* xvbf = xbf  + (size_t)N_NODE * 64;
    uint16_t* h1bf = xvbf + (size_t)N_NODE * 64;
    uint16_t* h0bf = h1bf + (size_t)B_SEED * S_NB * 64;
    uint16_t* Apre = xvbf;                                  // aliases xv region; dead after pgemm
    float* outp = (float*)d_out;

    prep_kernel<<<528, 256, 0, stream>>>(
        Wproj_u, Wnum_u, Wproj_i, Wnum_i, W_v, W_w, WTU, WTI, WvT0, WwT0);

    gpack_kernel<<<(N_NODE * 8 + 255) / 256, 256, 0, stream>>>(
        ufi, ifi, uti, iti, ufe, ife, wemb, Apre);

    pgemm_kernel<<<UBLK2 + IBLK2, 256, 0, stream>>>(
        Apre, u_id, i_id, uw300, iw300, is768, unum, inum,
        WTU, WTI, bproj_u, bnum_u, bproj_i, bnum_i, xbf);

    xv_kernel<<<(N_NODE + 63) / 64, 256, 0, stream>>>(xbf, WvT0, b_v, xvbf, N_NODE);

    sage_mfma_kernel<<<(B_SEED * S_NB) / 64, 256, 0, stream>>>(
        xbf, xvbf, neigh1, neigh2, WwT0, b_w, h1bf, 1);
    sage_mfma_kernel<<<B_SEED / 64, 256, 0, stream>>>(
        xbf, xvbf, seeds, neigh1, WwT0, b_w, h0bf, 1);

    final_kernel<<<B_SEED / 32, 256, 0, stream>>>(
        h0bf, h1bf, W_v + 4096, b_v + 64, W_w + 8192, b_w + 64, outp);
}

// Round 8
// 337.345 us; speedup vs baseline: 1.2408x; 1.1533x over previous
//
#include <hip/hip_runtime.h>
#include <hip/hip_bf16.h>
#include <stdint.h>

#define N_USER 100000
#define M_ITEM 50000
#define N_NODE 150000
#define B_SEED 2048
#define S_NB 20
#define UBLK2 1563           // ceil(100000/64)
#define IBLK2 782            // ceil(50000/64)

typedef __bf16   bf16x8 __attribute__((ext_vector_type(8)));
typedef float    f32x4  __attribute__((ext_vector_type(4)));
typedef uint32_t u32x4  __attribute__((ext_vector_type(4)));

typedef __attribute__((address_space(3))) uint32_t lds_u32_t;
typedef __attribute__((address_space(1))) const uint32_t glb_u32_t;

__device__ __forceinline__ uint16_t f2bf(float f) {
    uint32_t u = __float_as_uint(f);
    return (uint16_t)((u + 0x7FFFu + ((u >> 16) & 1u)) >> 16);   // RNE
}
__device__ __forceinline__ uint32_t pk2(float a, float b) {      // packed HW cvt (RNE)
    __hip_bfloat162 h = __float22bfloat162_rn(make_float2(a, b));
    return *reinterpret_cast<uint32_t*>(&h);
}
__device__ __forceinline__ float bf2f(uint16_t u) {
    return __uint_as_float(((uint32_t)u) << 16);
}

union BF8 { bf16x8 v; uint32_t u[4]; };

__device__ __forceinline__ bf16x8 pack8v(f32x4 lo, f32x4 hi) {
    BF8 r;
    r.u[0] = pk2(lo[0], lo[1]); r.u[1] = pk2(lo[2], lo[3]);
    r.u[2] = pk2(hi[0], hi[1]); r.u[3] = pk2(hi[2], hi[3]);
    return r.v;
}
__device__ __forceinline__ bf16x8 ldf32x8_mask(const float* rowp, int base, int limit) {
    BF8 r;
#pragma unroll
    for (int h = 0; h < 4; ++h) {
        const int k0 = base + 2 * h;
        const float a = (k0     < limit) ? rowp[k0]     : 0.f;
        const float b = (k0 + 1 < limit) ? rowp[k0 + 1] : 0.f;
        r.u[h] = pk2(a, b);
    }
    return r.v;
}

// ---------------------------------------------------------------------------
// prep: permuted-K transposed weights (bf16).
// k' [0,160): Apre (feat 64 | text 96)  -> orig Wproj rows 64..223
// k' [160,192): numeric (10 valid)      -> Wnum rows 0..9
// k' [192,224): word300 tail (12 valid) -> Wproj rows 512..523
// k' [224,288): id                      -> Wproj rows 0..63
// k' [288,576): word300 cols 0..287     -> Wproj rows 224..511
// k' [576,1344): sent768 (items)        -> Wproj rows 524..1291
// ---------------------------------------------------------------------------
__global__ void prep_kernel(const float* __restrict__ Wproj_u, const float* __restrict__ Wnum_u,
                            const float* __restrict__ Wproj_i, const float* __restrict__ Wnum_i,
                            const float* __restrict__ Wv0, const float* __restrict__ Ww0,
                            uint16_t* __restrict__ WTU, uint16_t* __restrict__ WTI,
                            uint16_t* __restrict__ WvT, uint16_t* __restrict__ WwT)
{
    const int idx = blockIdx.x * 256 + threadIdx.x;   // exactly 135168
    if (idx < 36864) {
        const int d = idx / 576, kp = idx - d * 576;
        float v = 0.f;
        if (kp < 160)      v = Wproj_u[(64 + kp) * 64 + d];
        else if (kp < 192) { const int j = kp - 160; if (j < 10) v = Wnum_u[j * 64 + d]; }
        else if (kp < 224) { const int j = kp - 192; if (j < 12) v = Wproj_u[(512 + j) * 64 + d]; }
        else if (kp < 288) v = Wproj_u[(kp - 224) * 64 + d];
        else               v = Wproj_u[(224 + kp - 288) * 64 + d];
        WTU[d * 576 + kp] = f2bf(v);
    } else if (idx < 122880) {
        const int i2 = idx - 36864;
        const int d = i2 / 1344, kp = i2 - d * 1344;
        float v = 0.f;
        if (kp < 160)      v = Wproj_i[(64 + kp) * 64 + d];
        else if (kp < 192) { const int j = kp - 160; if (j < 10) v = Wnum_i[j * 64 + d]; }
        else if (kp < 224) { const int j = kp - 192; if (j < 12) v = Wproj_i[(512 + j) * 64 + d]; }
        else if (kp < 288) v = Wproj_i[(kp - 224) * 64 + d];
        else if (kp < 576) v = Wproj_i[(224 + kp - 288) * 64 + d];
        else               v = Wproj_i[(524 + kp - 576) * 64 + d];
        WTI[d * 1344 + kp] = f2bf(v);
    } else {
        const int i2 = idx - 122880;
        if (i2 < 4096) { const int d = i2 >> 6, k = i2 & 63;  WvT[d * 64 + k]  = f2bf(Wv0[k * 64 + d]); }
        else           { const int j = i2 - 4096;
                         const int d = j >> 7, k = j & 127;   WwT[d * 128 + k] = f2bf(Ww0[k * 64 + d]); }
    }
}

// ---------------------------------------------------------------------------
// gpack: gathered segments -> A_pre[node][160] bf16 (8 threads per node).
// ---------------------------------------------------------------------------
__global__ __launch_bounds__(256) void gpack_kernel(
    const int* __restrict__ ufi, const int* __restrict__ ifi,
    const int* __restrict__ uti, const int* __restrict__ iti,
    const float* __restrict__ ufe, const float* __restrict__ ife,
    const float* __restrict__ wemb,
    uint16_t* __restrict__ Apre)
{
    const int gid  = blockIdx.x * 256 + threadIdx.x;
    const int node = gid >> 3;
    const int d0   = gid & 7;
    if (node >= N_NODE) return;
    const bool item = node >= N_USER;
    const int nloc  = item ? node - N_USER : node;
    const int*   fidx = (item ? ifi : ufi) + (size_t)nloc * 10;
    const int*   tidx = (item ? iti : uti) + (size_t)nloc * 24;
    const float* fe   = item ? ife : ufe;
    uint16_t* out = Apre + (size_t)node * 160;

    {
        f32x4 s0 = {0, 0, 0, 0}, s1 = {0, 0, 0, 0};
#pragma unroll
        for (int j = 0; j < 10; ++j) {
            const float* p = fe + (size_t)fidx[j] * 64 + 8 * d0;
            s0 += *(const f32x4*)p;
            s1 += *(const f32x4*)(p + 4);
        }
        s0 *= 0.1f; s1 *= 0.1f;
        uint4 o = make_uint4(pk2(s0[0], s0[1]), pk2(s0[2], s0[3]),
                             pk2(s1[0], s1[1]), pk2(s1[2], s1[3]));
        *(uint4*)(out + 8 * d0) = o;
    }
#pragma unroll
    for (int s = 0; s < 3; ++s) {
        f32x4 a = {0, 0, 0, 0};
#pragma unroll
        for (int j = 0; j < 8; ++j) {
            const float* p = wemb + (size_t)tidx[s * 8 + j] * 32 + 4 * d0;
            a += *(const f32x4*)p;
        }
        a *= 0.125f;
        *(uint2*)(out + 64 + 32 * s + 4 * d0) = make_uint2(pk2(a[0], a[1]), pk2(a[2], a[3]));
    }
}

// ---------------------------------------------------------------------------
// pgemm: LDS-staged streaming GEMM. Block = 64 nodes. Staged f32 chunks
// (32 cols) via global_load_lds (dwordx4), double-buffered, XOR-swizzled at
// 16B granule: col16B ^= (row&7)  [applied on global src AND ds_read].
// Items are blocks [0, IBLK2); users follow.
// ---------------------------------------------------------------------------
__global__ __launch_bounds__(256, 6) void pgemm_kernel(
    const uint16_t* __restrict__ Apre,
    const float* __restrict__ u_id,  const float* __restrict__ i_id,
    const float* __restrict__ uw300, const float* __restrict__ iw300,
    const float* __restrict__ is768,
    const float* __restrict__ unum,  const float* __restrict__ inum,
    const uint16_t* __restrict__ WTU, const uint16_t* __restrict__ WTI,
    const float* __restrict__ bproj_u, const float* __restrict__ bnum_u,
    const float* __restrict__ bproj_i, const float* __restrict__ bnum_i,
    uint16_t* __restrict__ xout)
{
    __shared__ float buf[2][2048];   // 2 x (64 rows x 32 f32) = 16 KB

    const int t = threadIdx.x;
    const int w = t >> 6, l = t & 63;
    const int l15 = l & 15, g4 = l >> 4;
    const bool item = blockIdx.x < IBLK2;
    const int tile  = item ? blockIdx.x : (blockIdx.x - IBLK2);
    const int ntype = item ? M_ITEM : N_USER;
    const int nb    = tile * 64;
    const int NC    = item ? 35 : 11;

    const float* idp = item ? i_id  : u_id;
    const float* w3p = item ? iw300 : uw300;
    const float* nmp = item ? inum  : unum;
    const uint16_t* WT = item ? WTI : WTU;
    const int KP       = item ? 1344 : 576;

    f32x4 acc[4] = {};
    const uint16_t* WTb = WT + (size_t)l15 * KP + g4 * 8;

    auto MM = [&](bf16x8 af, int kb) {
#pragma unroll
        for (int db = 0; db < 4; ++db) {
            const bf16x8 bfr = *reinterpret_cast<const bf16x8*>(WTb + (size_t)db * 16 * KP + kb);
            acc[db] = __builtin_amdgcn_mfma_f32_16x16x32_bf16(af, bfr, acc[db], 0, 0, 0);
        }
    };

    // chunk c -> source (base, stride, coloff):  c<2 id | c<11 w300 | else s768
    auto stage = [&](int bi, int c) {
        const float* base; int stride, coloff;
        if (c < 2)       { base = idp;    stride = 64;  coloff = c * 32; }
        else if (c < 11) { base = w3p;    stride = 300; coloff = (c - 2) * 32; }
        else             { base = is768;  stride = 768; coloff = (c - 11) * 32; }
#pragma unroll
        for (int j = 0; j < 2; ++j) {
            const int row  = w * 16 + j * 8 + (l >> 3);
            const int node = (nb + row) < ntype ? (nb + row) : (ntype - 1);
            const int swb  = ((l & 7) * 16) ^ ((row & 7) << 4);   // swizzled byte-in-row
            const float* g = base + (size_t)node * stride + coloff + (swb >> 2);
            uint32_t* lp = (uint32_t*)((char*)&buf[bi][0] + w * 2048 + j * 1024);
            __builtin_amdgcn_global_load_lds((glb_u32_t*)g, (lds_u32_t*)lp, 16, 0, 0);
        }
    };

    auto compute = [&](int bi, int kb) {
        const char* bb = (const char*)&buf[bi][0];
        const int r = w * 16 + l15;
        const f32x4 lo = *(const f32x4*)(bb + r * 128 + ((g4 * 32)      ^ ((r & 7) << 4)));
        const f32x4 hi = *(const f32x4*)(bb + r * 128 + ((g4 * 32 + 16) ^ ((r & 7) << 4)));
        MM(pack8v(lo, hi), kb);
    };

    // ---- prologue: stage chunk 0, then register-path MFMAs overlap it ----
    stage(0, 0);
    {
        const int nloc = (nb + w * 16 + l15) < ntype ? (nb + w * 16 + l15) : (ntype - 1);
        const int node = (item ? N_USER : 0) + nloc;
        const uint16_t* ap = Apre + (size_t)node * 160 + g4 * 8;
        bf16x8 af[5];
#pragma unroll
        for (int ks = 0; ks < 5; ++ks) af[ks] = *(const bf16x8*)(ap + ks * 32);
#pragma unroll
        for (int ks = 0; ks < 5; ++ks) MM(af[ks], ks * 32);
        MM(ldf32x8_mask(nmp + (size_t)nloc * 10, g4 * 8, 10), 160);
        MM(ldf32x8_mask(w3p + (size_t)nloc * 300, 288 + g4 * 8, 300), 192);
    }

    // ---- staged main loop (m97 two-barrier structure) ----
    for (int c = 0; c < NC; ++c) {
        if (c + 1 < NC) stage((c + 1) & 1, c + 1);
        __syncthreads();
        compute(c & 1, 224 + 32 * c);
        __syncthreads();
    }

    // ---- epilogue: row = g4*4+r (node-in-64), col d = db*16+l15 ----
    const int nb_out = nb + w * 16 + g4 * 4;
    const float* bp = item ? bproj_i : bproj_u;
    const float* bn = item ? bnum_i  : bnum_u;
    uint16_t* xo = xout + (size_t)(item ? N_USER : 0) * 64;
#pragma unroll
    for (int db = 0; db < 4; ++db) {
        const int d = db * 16 + l15;
        const float bias = bp[d] + bn[d];
#pragma unroll
        for (int r = 0; r < 4; ++r) {
            const int nn = nb_out + r;
            if (nn < ntype) xo[(size_t)nn * 64 + d] = f2bf(acc[db][r] + bias);
        }
    }
}

// ---------------------------------------------------------------------------
// xv = x @ Wv0 + bv0   (bf16 in/out, per node)
// ---------------------------------------------------------------------------
__global__ __launch_bounds__(256) void xv_kernel(
    const uint16_t* __restrict__ x, const uint16_t* __restrict__ WvT,
    const float* __restrict__ bv, uint16_t* __restrict__ xv, int n)
{
    const int t = threadIdx.x;
    const int w = t >> 6, l = t & 63, l15 = l & 15, g4 = l >> 4;
    const int node = blockIdx.x * 64 + w * 16 + l15;
    const int node_c = node < n ? node : n - 1;

    f32x4 acc[4] = {};
    const uint16_t* WTb = WvT + l15 * 64 + g4 * 8;
#pragma unroll
    for (int ks = 0; ks < 2; ++ks) {
        const bf16x8 af = *reinterpret_cast<const bf16x8*>(x + (size_t)node_c * 64 + ks * 32 + g4 * 8);
#pragma unroll
        for (int db = 0; db < 4; ++db) {
            const bf16x8 bfr = *reinterpret_cast<const bf16x8*>(WTb + db * 16 * 64 + ks * 32);
            acc[db] = __builtin_amdgcn_mfma_f32_16x16x32_bf16(af, bfr, acc[db], 0, 0, 0);
        }
    }
    const int node_base = blockIdx.x * 64 + w * 16 + g4 * 4;
#pragma unroll
    for (int db = 0; db < 4; ++db) {
        const int d = db * 16 + l15;
        const float bias = bv[d];
#pragma unroll
        for (int r = 0; r < 4; ++r) {
            const int nn = node_base + r;
            if (nn < n) xv[(size_t)nn * 64 + d] = f2bf(acc[db][r] + bias);
        }
    }
}

// ---------------------------------------------------------------------------
// SAGE layer-0 (MFMA): out[r] = act( [ x[self[r]] | mean_j xv[neigh[r,j]] ] @ Ww0 + bw0 )
// ---------------------------------------------------------------------------
__global__ __launch_bounds__(256) void sage_mfma_kernel(
    const uint16_t* __restrict__ x, const uint16_t* __restrict__ xv,
    const int* __restrict__ self_idx, const int* __restrict__ neigh_idx,
    const uint16_t* __restrict__ WwT, const float* __restrict__ bw,
    uint16_t* __restrict__ out, int relu)
{
    const int t = threadIdx.x;
    const int w = t >> 6, l = t & 63, l15 = l & 15, g4 = l >> 4;
    const int r = blockIdx.x * 64 + w * 16 + l15;
    const int sidx = self_idx[r];
    const int* ni = neigh_idx + (size_t)r * S_NB;

    f32x4 acc[4] = {};
    const uint16_t* WTb = WwT + l15 * 128 + g4 * 8;

    auto MM = [&](bf16x8 af, int kb) {
#pragma unroll
        for (int db = 0; db < 4; ++db) {
            const bf16x8 bfr = *reinterpret_cast<const bf16x8*>(WTb + db * 16 * 128 + kb);
            acc[db] = __builtin_amdgcn_mfma_f32_16x16x32_bf16(af, bfr, acc[db], 0, 0, 0);
        }
    };

#pragma unroll
    for (int ks = 0; ks < 2; ++ks) {
        const bf16x8 af = *reinterpret_cast<const bf16x8*>(x + (size_t)sidx * 64 + ks * 32 + g4 * 8);
        MM(af, ks * 32);
    }
#pragma unroll
    for (int ks = 0; ks < 2; ++ks) {
        float ev[4] = {0.f, 0.f, 0.f, 0.f}, od[4] = {0.f, 0.f, 0.f, 0.f};
#pragma unroll
        for (int j = 0; j < S_NB; ++j) {
            const u32x4 v = *reinterpret_cast<const u32x4*>(xv + (size_t)ni[j] * 64 + ks * 32 + g4 * 8);
#pragma unroll
            for (int q = 0; q < 4; ++q) {
                ev[q] += __uint_as_float(v[q] << 16);
                od[q] += __uint_as_float(v[q] & 0xffff0000u);
            }
        }
        BF8 m;
#pragma unroll
        for (int q = 0; q < 4; ++q) m.u[q] = pk2(ev[q] * (1.f / S_NB), od[q] * (1.f / S_NB));
        MM(m.v, 64 + ks * 32);
    }

    const int rb = blockIdx.x * 64 + w * 16 + g4 * 4;
#pragma unroll
    for (int db = 0; db < 4; ++db) {
        const int d = db * 16 + l15;
        const float bias = bw[d];
#pragma unroll
        for (int rr = 0; rr < 4; ++rr) {
            float h = acc[db][rr] + bias;
            if (relu) h = fmaxf(h, 0.f);
            out[(size_t)(rb + rr) * 64 + d] = f2bf(h);
        }
    }
}

// ---------------------------------------------------------------------------
// Final layer (fp32 shfl GEMV, 2048 rows)
// ---------------------------------------------------------------------------
__global__ __launch_bounds__(256) void final_kernel(
    const uint16_t* __restrict__ h0, const uint16_t* __restrict__ h1,
    const float* __restrict__ Wv, const float* __restrict__ bv,
    const float* __restrict__ Ww, const float* __restrict__ bw,
    float* __restrict__ out)
{
    __shared__ float WvL[64 * 64];
    __shared__ float WwL[128 * 64];
    const int t = threadIdx.x;
    for (int i = t; i < 64 * 64; i += 256)  WvL[i] = Wv[i];
    for (int i = t; i < 128 * 64; i += 256) WwL[i] = Ww[i];
    __syncthreads();

    const int wave = t >> 6, lane = t & 63;
    const int base = blockIdx.x * 32 + wave * 8;
    const float bvl = bv[lane], bwl = bw[lane];

    for (int i = 0; i < 8; ++i) {
        const int b = base + i;
        float m = 0.f;
#pragma unroll
        for (int s = 0; s < S_NB; ++s)
            m += bf2f(h1[(size_t)(b * S_NB + s) * 64 + lane]);
        m *= (1.f / S_NB);

        float agg = bvl;
#pragma unroll 8
        for (int k = 0; k < 64; ++k)
            agg += __shfl(m, k) * WvL[k * 64 + lane];

        const float selfv = bf2f(h0[(size_t)b * 64 + lane]);
        float h = bwl;
#pragma unroll 8
        for (int k = 0; k < 64; ++k)
            h += __shfl(selfv, k) * WwL[k * 64 + lane];
#pragma unroll 8
        for (int k = 0; k < 64; ++k)
            h += __shfl(agg, k) * WwL[(64 + k) * 64 + lane];

        out[(size_t)b * 64 + lane] = h;
    }
}

// ---------------------------------------------------------------------------
extern "C" void kernel_launch(void* const* d_in, const int* in_sizes, int n_in,
                              void* d_out, int out_size, void* d_ws, size_t ws_size,
                              hipStream_t stream)
{
    const int*   seeds   = (const int*)d_in[0];
    const int*   neigh1  = (const int*)d_in[1];
    const int*   neigh2  = (const int*)d_in[2];
    const int*   ufi     = (const int*)d_in[3];
    const int*   ifi     = (const int*)d_in[4];
    const int*   uti     = (const int*)d_in[5];
    const int*   iti     = (const int*)d_in[6];
    const float* u_id    = (const float*)d_in[7];
    const float* i_id    = (const float*)d_in[8];
    const float* ufe     = (const float*)d_in[9];
    const float* ife     = (const float*)d_in[10];
    const float* wemb    = (const float*)d_in[11];
    const float* uw300   = (const float*)d_in[12];
    const float* iw300   = (const float*)d_in[13];
    const float* is768   = (const float*)d_in[14];
    const float* unum    = (const float*)d_in[15];
    const float* inum    = (const float*)d_in[16];
    const float* Wnum_u  = (const float*)d_in[17];
    const float* bnum_u  = (const float*)d_in[18];
    const float* Wnum_i  = (const float*)d_in[19];
    const float* bnum_i  = (const float*)d_in[20];
    const float* Wproj_u = (const float*)d_in[21];
    const float* bproj_u = (const float*)d_in[22];
    const float* Wproj_i = (const float*)d_in[23];
    const float* bproj_i = (const float*)d_in[24];
    const float* W_w     = (const float*)d_in[25];
    const float* b_w     = (const float*)d_in[26];
    const float* W_v     = (const float*)d_in[27];
    const float* b_v     = (const float*)d_in[28];

    // ws layout (uint16 elements):
    // WTU | WTI | WvT0 | WwT0 | xbf | UNION{ xvbf|h1bf|h0bf , A_pre }
    uint16_t* WTU  = (uint16_t*)d_ws;                       // 64*576
    uint16_t* WTI  = WTU  + 36864;                          // 64*1344
    uint16_t* WvT0 = WTI  + 86016;                          // 64*64
    uint16_t* WwT0 = WvT0 + 4096;                           // 64*128
    uint16_t* xbf  = WwT0 + 8192;                           // 150000*64
    uint16_t* xvbf = xbf  + (size_t)N_NODE * 64;
    uint16_t* h1bf = xvbf + (size_t)N_NODE * 64;
    uint16_t* h0bf = h1bf + (size_t)B_SEED * S_NB * 64;
    uint16_t* Apre = xvbf;                                  // aliases xv region; dead after pgemm
    float* outp = (float*)d_out;

    prep_kernel<<<528, 256, 0, stream>>>(
        Wproj_u, Wnum_u, Wproj_i, Wnum_i, W_v, W_w, WTU, WTI, WvT0, WwT0);

    gpack_kernel<<<(N_NODE * 8 + 255) / 256, 256, 0, stream>>>(
        ufi, ifi, uti, iti, ufe, ife, wemb, Apre);

    pgemm_kernel<<<UBLK2 + IBLK2, 256, 0, stream>>>(
        Apre, u_id, i_id, uw300, iw300, is768, unum, inum,
        WTU, WTI, bproj_u, bnum_u, bproj_i, bnum_i, xbf);

    xv_kernel<<<(N_NODE + 63) / 64, 256, 0, stream>>>(xbf, WvT0, b_v, xvbf, N_NODE);

    sage_mfma_kernel<<<(B_SEED * S_NB) / 64, 256, 0, stream>>>(
        xbf, xvbf, neigh1, neigh2, WwT0, b_w, h1bf, 1);
    sage_mfma_kernel<<<B_SEED / 64, 256, 0, stream>>>(
        xbf, xvbf, seeds, neigh1, WwT0, b_w, h0bf, 1);

    final_kernel<<<B_SEED / 32, 256, 0, stream>>>(
        h0bf, h1bf, W_v + 4096, b_v + 64, W_w + 8192, b_w + 64, outp);
}